// Round 7
// baseline (1914.755 us; speedup 1.0000x reference)
//
#include <hip/hip_runtime.h>
#include <hip/hip_bf16.h>

typedef __bf16 bf16x8 __attribute__((ext_vector_type(8)));
typedef float floatx4 __attribute__((ext_vector_type(4)));
typedef int   intx4  __attribute__((ext_vector_type(4)));
typedef unsigned long long ull;

#define B_ 16
#define N_ 512
#define I_ 512
#define H_ 1024

// workspace byte offsets
constexpr size_t OFF_TT  = 0;                               // Tt bf16 (dead after v_gemm)
constexpr size_t OFF_V   = OFF_TT + 3ull * H_ * H_ * 2;     // V bf16
constexpr size_t OFF_F0  = OFF_V + 3ull * H_ * H_ * 2;      // f0,o0,z0 fp32
constexpr size_t OFF_C   = OFF_F0 + 3ull * B_ * H_ * 4;     // tree_c fp32
constexpr size_t OFF_HBF = OFF_C + (size_t)B_ * N_ * H_ * 4;// h bf16 shadow

// worklist region (inside dead Tt region; written by prep after v_gemm)
constexpr size_t OFF_BAR   = OFF_TT;                        // barrier counter
constexpr size_t OFF_PAIRS = OFF_TT + 1024;                 // 8176 packed pairs
constexpr size_t OFF_LOFF  = OFF_PAIRS + 32768;             // offs[0..512], maxlvl at [513]

// scan dynamic LDS layout
constexpr size_t L_A    = 0;                                // A tile: 32768
constexpr size_t L_VS   = 32768;                            // swizzled V: 3*32*64*16 = 98304
constexpr size_t L_C2   = 131072;                           // ldsC: 3*16*17*4 = 3264
constexpr size_t L_TOT  = 134336;

#define NPAIRS (B_ * (N_ - 1))

#define AT_ST(p, v)  __hip_atomic_store((p), (v), __ATOMIC_RELAXED, __HIP_MEMORY_SCOPE_AGENT)

// ---------------------------------------------------------------------------
// Kernel 1: Tt[g][j][k] = bf16(T_g[k][j])
// ---------------------------------------------------------------------------
__global__ void __launch_bounds__(256)
t_transpose(const float* __restrict__ Tf, const float* __restrict__ To,
            const float* __restrict__ Tz, char* __restrict__ ws)
{
    __shared__ float tile[64][65];
    int g   = blockIdx.x >> 8;
    int rem = blockIdx.x & 255;
    int tj = rem >> 4, tk = rem & 15;
    const float* T = (g == 0) ? Tf : (g == 1) ? To : Tz;
    int c  = threadIdx.x & 63;
    int r0 = threadIdx.x >> 6;
#pragma unroll
    for (int l = 0; l < 16; ++l) {
        int r = l * 4 + r0;
        tile[r][c] = T[(size_t)(tk * 64 + r) * H_ + tj * 64 + c];
    }
    __syncthreads();
    __hip_bfloat16* Tt = (__hip_bfloat16*)(ws + OFF_TT) + (size_t)g * H_ * H_;
#pragma unroll
    for (int l = 0; l < 16; ++l) {
        int rr = l * 4 + r0;
        Tt[(size_t)(tj * 64 + rr) * H_ + tk * 64 + c] = __float2bfloat16(tile[c][rr]);
    }
}

// ---------------------------------------------------------------------------
// Kernel 2: root node -- f0/o0/z0 = x0 @ W + b ; root h,c ; bf16 h shadow
// ---------------------------------------------------------------------------
__global__ void __launch_bounds__(256)
k0_root(const float* __restrict__ te,
        const float* __restrict__ Wf, const float* __restrict__ bfv,
        const float* __restrict__ Wo, const float* __restrict__ bov,
        const float* __restrict__ Wz, const float* __restrict__ bzv,
        float* __restrict__ out, char* __restrict__ ws)
{
    __shared__ float x0[I_];
    int b = blockIdx.x >> 2;
    int h = ((blockIdx.x & 3) << 8) + threadIdx.x;
    for (int k = threadIdx.x; k < I_; k += 256)
        x0[k] = te[(size_t)b * N_ * I_ + k];
    __syncthreads();
    float af = bfv[h], ao = bov[h], az = bzv[h];
#pragma unroll 4
    for (int k = 0; k < I_; ++k) {
        float x = x0[k];
        af = fmaf(x, Wf[k * H_ + h], af);
        ao = fmaf(x, Wo[k * H_ + h], ao);
        az = fmaf(x, Wz[k * H_ + h], az);
    }
    float* f0 = (float*)(ws + OFF_F0);
    f0[b * H_ + h]               = af;
    f0[B_ * H_ + b * H_ + h]     = ao;
    f0[2 * B_ * H_ + b * H_ + h] = az;
    float f = 1.0f / (1.0f + __expf(-af));
    float o = 1.0f / (1.0f + __expf(-ao));
    float z = tanhf(az);
    float c = z * (1.0f - f);
    float hh = o * tanhf(c);
    size_t idx = (size_t)b * N_ * H_ + h;
    ((float*)(ws + OFF_C))[idx] = c;
    out[idx] = hh;
    ((__hip_bfloat16*)(ws + OFF_HBF))[idx] = __float2bfloat16(hh);
}

// ---------------------------------------------------------------------------
// Kernel 3: V_g = Tt_g · Tt_g^T, 64x64 output per wave
// ---------------------------------------------------------------------------
__global__ void __launch_bounds__(64)
v_gemm(char* __restrict__ ws)
{
    int blk = blockIdx.x;
    int g   = blk >> 8;
    int rem = blk & 255;
    int mg = rem >> 4, ng = rem & 15;
    int lane = threadIdx.x;
    int q = lane >> 4, m = lane & 15;
    const __bf16* Tt = (const __bf16*)(ws + OFF_TT) + (size_t)g * H_ * H_;
    const __bf16* pa = Tt + (size_t)(mg * 64 + m) * H_ + q * 8;
    const __bf16* pb = Tt + (size_t)(ng * 64 + m) * H_ + q * 8;

    floatx4 acc[4][4];
#pragma unroll
    for (int ti = 0; ti < 4; ++ti)
#pragma unroll
        for (int tj = 0; tj < 4; ++tj)
            acc[ti][tj] = (floatx4){0.f, 0.f, 0.f, 0.f};

#pragma unroll 2
    for (int c = 0; c < 32; ++c) {
        bf16x8 a0 = *(const bf16x8*)(pa + c * 32);
        bf16x8 a1 = *(const bf16x8*)(pa + 16 * H_ + c * 32);
        bf16x8 a2 = *(const bf16x8*)(pa + 32 * H_ + c * 32);
        bf16x8 a3 = *(const bf16x8*)(pa + 48 * H_ + c * 32);
        bf16x8 b0 = *(const bf16x8*)(pb + c * 32);
        bf16x8 b1 = *(const bf16x8*)(pb + 16 * H_ + c * 32);
        bf16x8 b2 = *(const bf16x8*)(pb + 32 * H_ + c * 32);
        bf16x8 b3 = *(const bf16x8*)(pb + 48 * H_ + c * 32);
        acc[0][0] = __builtin_amdgcn_mfma_f32_16x16x32_bf16(a0, b0, acc[0][0], 0, 0, 0);
        acc[0][1] = __builtin_amdgcn_mfma_f32_16x16x32_bf16(a0, b1, acc[0][1], 0, 0, 0);
        acc[0][2] = __builtin_amdgcn_mfma_f32_16x16x32_bf16(a0, b2, acc[0][2], 0, 0, 0);
        acc[0][3] = __builtin_amdgcn_mfma_f32_16x16x32_bf16(a0, b3, acc[0][3], 0, 0, 0);
        acc[1][0] = __builtin_amdgcn_mfma_f32_16x16x32_bf16(a1, b0, acc[1][0], 0, 0, 0);
        acc[1][1] = __builtin_amdgcn_mfma_f32_16x16x32_bf16(a1, b1, acc[1][1], 0, 0, 0);
        acc[1][2] = __builtin_amdgcn_mfma_f32_16x16x32_bf16(a1, b2, acc[1][2], 0, 0, 0);
        acc[1][3] = __builtin_amdgcn_mfma_f32_16x16x32_bf16(a1, b3, acc[1][3], 0, 0, 0);
        acc[2][0] = __builtin_amdgcn_mfma_f32_16x16x32_bf16(a2, b0, acc[2][0], 0, 0, 0);
        acc[2][1] = __builtin_amdgcn_mfma_f32_16x16x32_bf16(a2, b1, acc[2][1], 0, 0, 0);
        acc[2][2] = __builtin_amdgcn_mfma_f32_16x16x32_bf16(a2, b2, acc[2][2], 0, 0, 0);
        acc[2][3] = __builtin_amdgcn_mfma_f32_16x16x32_bf16(a2, b3, acc[2][3], 0, 0, 0);
        acc[3][0] = __builtin_amdgcn_mfma_f32_16x16x32_bf16(a3, b0, acc[3][0], 0, 0, 0);
        acc[3][1] = __builtin_amdgcn_mfma_f32_16x16x32_bf16(a3, b1, acc[3][1], 0, 0, 0);
        acc[3][2] = __builtin_amdgcn_mfma_f32_16x16x32_bf16(a3, b2, acc[3][2], 0, 0, 0);
        acc[3][3] = __builtin_amdgcn_mfma_f32_16x16x32_bf16(a3, b3, acc[3][3], 0, 0, 0);
    }
    __hip_bfloat16* V = (__hip_bfloat16*)(ws + OFF_V) + (size_t)g * H_ * H_;
#pragma unroll
    for (int ti = 0; ti < 4; ++ti)
#pragma unroll
        for (int tj = 0; tj < 4; ++tj)
#pragma unroll
            for (int rr = 0; rr < 4; ++rr)
                V[(size_t)(mg * 64 + ti * 16 + q * 4 + rr) * H_ + ng * 64 + tj * 16 + m]
                    = __float2bfloat16(acc[ti][tj][rr]);
}

// ---------------------------------------------------------------------------
// Kernel 4: prep -- levels, counting-sort worklist, zero barrier. Single WG.
// ---------------------------------------------------------------------------
__global__ void __launch_bounds__(256)
prep(const int* __restrict__ conn, char* __restrict__ ws)
{
    __shared__ int            conn_s[B_ * N_];
    __shared__ unsigned short lvl[B_ * N_];
    __shared__ int            hist[N_];
    __shared__ int            offs[N_ + 1];
    __shared__ int            cursor[N_];
    __shared__ int            mlv;

    int t = threadIdx.x;
    for (int idx = t; idx < B_ * N_; idx += 256) conn_s[idx] = conn[idx];
    for (int l = t; l < N_; l += 256) hist[l] = 0;
    __syncthreads();
    if (t < B_) {
        int b = t;
        lvl[b * N_] = 0;
        for (int i = 1; i < N_; ++i)
            lvl[b * N_ + i] = lvl[b * N_ + conn_s[b * N_ + i]] + 1;
    }
    __syncthreads();
    for (int idx = t; idx < B_ * N_; idx += 256) {
        if (idx & (N_ - 1)) atomicAdd(&hist[lvl[idx]], 1);
    }
    __syncthreads();
    if (t == 0) {
        int s = 0, ml = 0;
        for (int l = 0; l < N_; ++l) {
            offs[l] = s; s += hist[l];
            if (hist[l] > 0) ml = l;
        }
        offs[N_] = s;
        mlv = ml;
        *(unsigned*)(ws + OFF_BAR) = 0u;
    }
    __syncthreads();
    for (int l = t; l < N_; l += 256) cursor[l] = offs[l];
    __syncthreads();
    int* gpairs = (int*)(ws + OFF_PAIRS);
    for (int idx = t; idx < B_ * N_; idx += 256) {
        int i = idx & (N_ - 1);
        if (i) {
            int b = idx >> 9;
            int L = lvl[idx];
            int pos = atomicAdd(&cursor[L], 1);
            gpairs[pos] = (b << 18) | (i << 9) | conn_s[idx];
        }
    }
    int* goffs = (int*)(ws + OFF_LOFF);
    for (int l = t; l <= N_; l += 256) goffs[l] = offs[l];
    if (t == 0) goffs[N_ + 1] = mlv;
}

// ---------------------------------------------------------------------------
// Kernel 5: level-scheduled scan. 256 WGs = 64 col-slices x 4 pair-groups.
// A-staging + parent-c now use PLAIN pipelined vector loads (safe: rows are
// line-exclusive per node, written only via sc1 write-through, never cached
// by any reader before the write, kernel starts with L2 invalidate; compiler
// motion blocked by __syncthreads fences + acquire barrier spin).
// Stores remain sc1 agent atomics. Barrier: release FAA + acquire spin with
// s_sleep backoff.
// ---------------------------------------------------------------------------
__global__ void __launch_bounds__(256, 1)
scan_kernel(float* __restrict__ out, char* __restrict__ ws)
{
    extern __shared__ char lds[];
    __bf16* aSwz   = (__bf16*)(lds + L_A);    // 32 KB swizzled A tile
    __bf16* swizzV = (__bf16*)(lds + L_VS);   // 96 KB swizzled V slice
    float*  ldsC   = (float*)(lds + L_C2);

    const int t    = threadIdx.x;
    const int wave = t >> 6;
    const int lane = t & 63;
    const int q = lane >> 4;
    const int m = lane & 15;
    const int cs = blockIdx.x & 63;         // column slice (16 H-cols)
    const int pg = blockIdx.x >> 6;         // pair group (0..3)

    const int* __restrict__ pairsG = (const int*)(ws + OFF_PAIRS);
    const int* __restrict__ offsG  = (const int*)(ws + OFF_LOFF);
    ull*       hbw = (ull*)(ws + OFF_HBF);
    const float* __restrict__ f0 = (const float*)(ws + OFF_F0);
    const float* __restrict__ o0 = f0 + B_ * H_;
    const float* __restrict__ z0 = o0 + B_ * H_;
    ull*      tcu = (ull*)(ws + OFF_C);
    float*    out_f = out;
    unsigned* bar = (unsigned*)(ws + OFF_BAR);

    // stage V swizzled: chunk j=(g,c,lane) -> V_g[row=cs*16+mm][k=c*32+qq*8..+7]
    const __bf16* Vg = (const __bf16*)(ws + OFF_V);
    for (int j = t; j < 6144; j += 256) {
        int g  = j >> 11;
        int c  = (j >> 6) & 31;
        int ln = j & 63;
        int qq = ln >> 4, mm = ln & 15;
        bf16x8 v = *(const bf16x8*)(Vg + (size_t)g * H_ * H_
                                       + (size_t)(cs * 16 + mm) * H_ + c * 32 + qq * 8);
        *(bf16x8*)(swizzV + (size_t)j * 8) = v;
    }
    __syncthreads();

    const int maxlvl = offsG[N_ + 1];
    const int rid = t & 15;                 // staged pair slot
    const int ck  = t >> 4;                 // 128B chunk within row
    char* stDst = (char*)aSwz + ck * 2048 + rid * 16;
    const char* aB = (const char*)aSwz + lane * 16;
    const __bf16* vbL = swizzV + ((size_t)(wave < 3 ? wave : 0) * 2048 + lane) * 8;
    const intx4* hbv = (const intx4*)(ws + OFF_HBF);

    for (int r = 1; r <= maxlvl; ++r) {
        const int lo = offsG[r], hi = offsG[r + 1];
        const int ntile = (hi - lo + 15) >> 4;
        for (int tt = pg; tt < ntile; tt += 4) {
            const int curTs = lo + (tt << 4);

            // A staging: 8x plain dwordx4 loads per thread (one 128B chunk),
            // pipelined into a single vmcnt window.
            int idx = curTs + rid; if (idx > hi - 1) idx = hi - 1;
            int pk = pairsG[idx];
            const intx4* src = hbv + ((((size_t)((pk >> 18) * N_ + (pk & 511))) * H_) >> 3)
                                   + (size_t)ck * 8;
            intx4 u0 = src[0], u1 = src[1], u2 = src[2], u3 = src[3];
            intx4 u4 = src[4], u5 = src[5], u6 = src[6], u7 = src[7];

            // wave3: parent-c prefetch for this tile (plain 16B load)
            floatx4 pcv = {0.f, 0.f, 0.f, 0.f};
            if (wave == 3) {
                int idx2 = curTs + (lane >> 2); if (idx2 > hi - 1) idx2 = hi - 1;
                int pk2 = pairsG[idx2];
                const float* pca = (const float*)(ws + OFF_C)
                    + ((size_t)((pk2 >> 18) * N_ + (pk2 & 511))) * H_
                    + cs * 16 + (lane & 3) * 4;
                pcv = *(const floatx4*)pca;
            }

            __syncthreads();                // S_a: prev tile fully consumed
            {
                intx4* d = (intx4*)stDst;
                d[0]  = u0; d[16] = u1; d[32] = u2; d[48] = u3;   // stride 256B
                d[64] = u4; d[80] = u5; d[96] = u6; d[112] = u7;
            }
            __syncthreads();                // S_b: aSwz visible

            if (wave < 3) {
                floatx4 acc0 = {0.f,0.f,0.f,0.f}, acc1 = {0.f,0.f,0.f,0.f};
                floatx4 acc2 = {0.f,0.f,0.f,0.f}, acc3 = {0.f,0.f,0.f,0.f};
#pragma unroll
                for (int c = 0; c < 32; ++c) {
                    bf16x8 av = *(const bf16x8*)(aB + c * 1024);
                    bf16x8 bv = *(const bf16x8*)(vbL + c * 512);
                    switch (c & 3) {
                    case 0:  acc0 = __builtin_amdgcn_mfma_f32_16x16x32_bf16(av, bv, acc0, 0, 0, 0); break;
                    case 1:  acc1 = __builtin_amdgcn_mfma_f32_16x16x32_bf16(av, bv, acc1, 0, 0, 0); break;
                    case 2:  acc2 = __builtin_amdgcn_mfma_f32_16x16x32_bf16(av, bv, acc2, 0, 0, 0); break;
                    default: acc3 = __builtin_amdgcn_mfma_f32_16x16x32_bf16(av, bv, acc3, 0, 0, 0); break;
                    }
                }
                floatx4 acc = (acc0 + acc1) + (acc2 + acc3);
                ldsC[(wave * 16 + q * 4 + 0) * 17 + m] = acc[0];
                ldsC[(wave * 16 + q * 4 + 1) * 17 + m] = acc[1];
                ldsC[(wave * 16 + q * 4 + 2) * 17 + m] = acc[2];
                ldsC[(wave * 16 + q * 4 + 3) * 17 + m] = acc[3];
            }
            __syncthreads();                // S_c: ldsC ready

            if (wave == 3) {
                int pr = lane >> 2, n0 = (lane & 3) << 2;
                int idx2 = curTs + pr; if (idx2 > hi - 1) idx2 = hi - 1;
                int pk2 = pairsG[idx2];
                int bb = pk2 >> 18, ii = (pk2 >> 9) & 511;
                int hcol0 = cs * 16 + n0;
                floatx4 fv = *(const floatx4*)&f0[bb * H_ + hcol0];
                floatx4 ov = *(const floatx4*)&o0[bb * H_ + hcol0];
                floatx4 zv = *(const floatx4*)&z0[bb * H_ + hcol0];
                floatx4 cc, hv;
                ull hpack = 0;
#pragma unroll
                for (int j = 0; j < 4; ++j) {
                    float af = ldsC[(0 * 16 + pr) * 17 + n0 + j] + fv[j];
                    float ao = ldsC[(1 * 16 + pr) * 17 + n0 + j] + ov[j];
                    float az = ldsC[(2 * 16 + pr) * 17 + n0 + j] + zv[j];
                    float f = 1.0f / (1.0f + __expf(-af));
                    float o = 1.0f / (1.0f + __expf(-ao));
                    float z = tanhf(az);
                    float c = pcv[j] * f + z * (1.0f - f);
                    float h = o * tanhf(c);
                    cc[j] = c; hv[j] = h;
                    hpack |= (ull)__builtin_bit_cast(unsigned short, __float2bfloat16(h)) << (16 * j);
                }
                size_t idxI = ((size_t)(bb * N_ + ii)) * H_ + hcol0;
                union U2 { ull u; float f[2]; };
                U2 c01, c23;
                c01.f[0] = cc[0]; c01.f[1] = cc[1];
                c23.f[0] = cc[2]; c23.f[1] = cc[3];
                AT_ST(tcu + (idxI >> 1),     c01.u);
                AT_ST(tcu + (idxI >> 1) + 1, c23.u);
                *(floatx4*)&out_f[idxI] = hv;
                AT_ST(hbw + (idxI >> 2), hpack);
            }
        }
        if (r < maxlvl) {
            __syncthreads();                // pre-barrier drain (compiler vmcnt0)
            if (t == 0) {
                __hip_atomic_fetch_add(bar, 1u, __ATOMIC_RELEASE, __HIP_MEMORY_SCOPE_AGENT);
                unsigned tgt = 256u * (unsigned)r;
                if (__hip_atomic_load(bar, __ATOMIC_ACQUIRE, __HIP_MEMORY_SCOPE_AGENT) < tgt) {
                    while (__hip_atomic_load(bar, __ATOMIC_ACQUIRE, __HIP_MEMORY_SCOPE_AGENT) < tgt)
                        __builtin_amdgcn_s_sleep(4);
                }
            }
            __syncthreads();
        }
    }
}

// ---------------------------------------------------------------------------
extern "C" void kernel_launch(void* const* d_in, const int* in_sizes, int n_in,
                              void* d_out, int out_size, void* d_ws, size_t ws_size,
                              hipStream_t stream)
{
    const float* te  = (const float*)d_in[0];
    const int*  conn = (const int*)d_in[1];
    const float* Wf = (const float*)d_in[3];
    const float* bf = (const float*)d_in[4];
    const float* Wo = (const float*)d_in[5];
    const float* bo = (const float*)d_in[6];
    const float* Wz = (const float*)d_in[7];
    const float* bz = (const float*)d_in[8];
    const float* Tf = (const float*)d_in[9];
    const float* To = (const float*)d_in[10];
    const float* Tz = (const float*)d_in[11];
    float* out = (float*)d_out;
    char*  ws  = (char*)d_ws;

    hipFuncSetAttribute((const void*)scan_kernel,
                        hipFuncAttributeMaxDynamicSharedMemorySize, (int)L_TOT);

    t_transpose<<<dim3(768), dim3(256), 0, stream>>>(Tf, To, Tz, ws);
    k0_root<<<dim3(64), dim3(256), 0, stream>>>(te, Wf, bf, Wo, bo, Wz, bz, out, ws);
    v_gemm<<<dim3(768), dim3(64), 0, stream>>>(ws);
    prep<<<dim3(1), dim3(256), 0, stream>>>(conn, ws);

    void* args[] = { (void*)&out, (void*)&ws };
    hipLaunchCooperativeKernel((const void*)scan_kernel, dim3(256), dim3(256),
                               (void**)args, (unsigned)L_TOT, stream);
}

// Round 8
// 1146.557 us; speedup vs baseline: 1.6700x; 1.6700x over previous
//
#include <hip/hip_runtime.h>
#include <hip/hip_bf16.h>

typedef __bf16 bf16x8 __attribute__((ext_vector_type(8)));
typedef float floatx4 __attribute__((ext_vector_type(4)));
typedef int   intx4  __attribute__((ext_vector_type(4)));
typedef unsigned long long ull;

#define B_ 16
#define N_ 512
#define I_ 512
#define H_ 1024

// workspace byte offsets
constexpr size_t OFF_TT  = 0;                               // Tt bf16 (dead after v_gemm)
constexpr size_t OFF_V   = OFF_TT + 3ull * H_ * H_ * 2;     // V bf16
constexpr size_t OFF_F0  = OFF_V + 3ull * H_ * H_ * 2;      // f0,o0,z0 fp32
constexpr size_t OFF_C   = OFF_F0 + 3ull * B_ * H_ * 4;     // tree_c fp32
constexpr size_t OFF_HBF = OFF_C + (size_t)B_ * N_ * H_ * 4;// h bf16 shadow

// worklist region (inside dead Tt region; written by prep after v_gemm)
constexpr size_t OFF_FLAGS = OFF_TT;                        // 256 per-WG round flags (1 KB)
constexpr size_t OFF_PAIRS = OFF_TT + 1024;                 // 8176 packed pairs
constexpr size_t OFF_LOFF  = OFF_PAIRS + 32768;             // offs[0..512], maxlvl at [513]

// scan dynamic LDS layout
constexpr size_t L_A    = 0;                                // A tile: 32768
constexpr size_t L_VS   = 32768;                            // swizzled V: 3*32*64*16 = 98304
constexpr size_t L_C2   = 131072;                           // ldsC: 3*16*17*4 = 3264
constexpr size_t L_TOT  = 134336;

#define NPAIRS (B_ * (N_ - 1))

#define AT_LD(p)     __hip_atomic_load((p), __ATOMIC_RELAXED, __HIP_MEMORY_SCOPE_AGENT)
#define AT_ST(p, v)  __hip_atomic_store((p), (v), __ATOMIC_RELAXED, __HIP_MEMORY_SCOPE_AGENT)

// ---------------------------------------------------------------------------
// Kernel 1: Tt[g][j][k] = bf16(T_g[k][j])
// ---------------------------------------------------------------------------
__global__ void __launch_bounds__(256)
t_transpose(const float* __restrict__ Tf, const float* __restrict__ To,
            const float* __restrict__ Tz, char* __restrict__ ws)
{
    __shared__ float tile[64][65];
    int g   = blockIdx.x >> 8;
    int rem = blockIdx.x & 255;
    int tj = rem >> 4, tk = rem & 15;
    const float* T = (g == 0) ? Tf : (g == 1) ? To : Tz;
    int c  = threadIdx.x & 63;
    int r0 = threadIdx.x >> 6;
#pragma unroll
    for (int l = 0; l < 16; ++l) {
        int r = l * 4 + r0;
        tile[r][c] = T[(size_t)(tk * 64 + r) * H_ + tj * 64 + c];
    }
    __syncthreads();
    __hip_bfloat16* Tt = (__hip_bfloat16*)(ws + OFF_TT) + (size_t)g * H_ * H_;
#pragma unroll
    for (int l = 0; l < 16; ++l) {
        int rr = l * 4 + r0;
        Tt[(size_t)(tj * 64 + rr) * H_ + tk * 64 + c] = __float2bfloat16(tile[c][rr]);
    }
}

// ---------------------------------------------------------------------------
// Kernel 2: root node -- f0/o0/z0 = x0 @ W + b ; root h,c ; bf16 h shadow
// ---------------------------------------------------------------------------
__global__ void __launch_bounds__(256)
k0_root(const float* __restrict__ te,
        const float* __restrict__ Wf, const float* __restrict__ bfv,
        const float* __restrict__ Wo, const float* __restrict__ bov,
        const float* __restrict__ Wz, const float* __restrict__ bzv,
        float* __restrict__ out, char* __restrict__ ws)
{
    __shared__ float x0[I_];
    int b = blockIdx.x >> 2;
    int h = ((blockIdx.x & 3) << 8) + threadIdx.x;
    for (int k = threadIdx.x; k < I_; k += 256)
        x0[k] = te[(size_t)b * N_ * I_ + k];
    __syncthreads();
    float af = bfv[h], ao = bov[h], az = bzv[h];
#pragma unroll 4
    for (int k = 0; k < I_; ++k) {
        float x = x0[k];
        af = fmaf(x, Wf[k * H_ + h], af);
        ao = fmaf(x, Wo[k * H_ + h], ao);
        az = fmaf(x, Wz[k * H_ + h], az);
    }
    float* f0 = (float*)(ws + OFF_F0);
    f0[b * H_ + h]               = af;
    f0[B_ * H_ + b * H_ + h]     = ao;
    f0[2 * B_ * H_ + b * H_ + h] = az;
    float f = 1.0f / (1.0f + __expf(-af));
    float o = 1.0f / (1.0f + __expf(-ao));
    float z = tanhf(az);
    float c = z * (1.0f - f);
    float hh = o * tanhf(c);
    size_t idx = (size_t)b * N_ * H_ + h;
    ((float*)(ws + OFF_C))[idx] = c;
    out[idx] = hh;
    ((__hip_bfloat16*)(ws + OFF_HBF))[idx] = __float2bfloat16(hh);
}

// ---------------------------------------------------------------------------
// Kernel 3: V_g = Tt_g · Tt_g^T, 64x64 output per wave
// ---------------------------------------------------------------------------
__global__ void __launch_bounds__(64)
v_gemm(char* __restrict__ ws)
{
    int blk = blockIdx.x;
    int g   = blk >> 8;
    int rem = blk & 255;
    int mg = rem >> 4, ng = rem & 15;
    int lane = threadIdx.x;
    int q = lane >> 4, m = lane & 15;
    const __bf16* Tt = (const __bf16*)(ws + OFF_TT) + (size_t)g * H_ * H_;
    const __bf16* pa = Tt + (size_t)(mg * 64 + m) * H_ + q * 8;
    const __bf16* pb = Tt + (size_t)(ng * 64 + m) * H_ + q * 8;

    floatx4 acc[4][4];
#pragma unroll
    for (int ti = 0; ti < 4; ++ti)
#pragma unroll
        for (int tj = 0; tj < 4; ++tj)
            acc[ti][tj] = (floatx4){0.f, 0.f, 0.f, 0.f};

#pragma unroll 2
    for (int c = 0; c < 32; ++c) {
        bf16x8 a0 = *(const bf16x8*)(pa + c * 32);
        bf16x8 a1 = *(const bf16x8*)(pa + 16 * H_ + c * 32);
        bf16x8 a2 = *(const bf16x8*)(pa + 32 * H_ + c * 32);
        bf16x8 a3 = *(const bf16x8*)(pa + 48 * H_ + c * 32);
        bf16x8 b0 = *(const bf16x8*)(pb + c * 32);
        bf16x8 b1 = *(const bf16x8*)(pb + 16 * H_ + c * 32);
        bf16x8 b2 = *(const bf16x8*)(pb + 32 * H_ + c * 32);
        bf16x8 b3 = *(const bf16x8*)(pb + 48 * H_ + c * 32);
        acc[0][0] = __builtin_amdgcn_mfma_f32_16x16x32_bf16(a0, b0, acc[0][0], 0, 0, 0);
        acc[0][1] = __builtin_amdgcn_mfma_f32_16x16x32_bf16(a0, b1, acc[0][1], 0, 0, 0);
        acc[0][2] = __builtin_amdgcn_mfma_f32_16x16x32_bf16(a0, b2, acc[0][2], 0, 0, 0);
        acc[0][3] = __builtin_amdgcn_mfma_f32_16x16x32_bf16(a0, b3, acc[0][3], 0, 0, 0);
        acc[1][0] = __builtin_amdgcn_mfma_f32_16x16x32_bf16(a1, b0, acc[1][0], 0, 0, 0);
        acc[1][1] = __builtin_amdgcn_mfma_f32_16x16x32_bf16(a1, b1, acc[1][1], 0, 0, 0);
        acc[1][2] = __builtin_amdgcn_mfma_f32_16x16x32_bf16(a1, b2, acc[1][2], 0, 0, 0);
        acc[1][3] = __builtin_amdgcn_mfma_f32_16x16x32_bf16(a1, b3, acc[1][3], 0, 0, 0);
        acc[2][0] = __builtin_amdgcn_mfma_f32_16x16x32_bf16(a2, b0, acc[2][0], 0, 0, 0);
        acc[2][1] = __builtin_amdgcn_mfma_f32_16x16x32_bf16(a2, b1, acc[2][1], 0, 0, 0);
        acc[2][2] = __builtin_amdgcn_mfma_f32_16x16x32_bf16(a2, b2, acc[2][2], 0, 0, 0);
        acc[2][3] = __builtin_amdgcn_mfma_f32_16x16x32_bf16(a2, b3, acc[2][3], 0, 0, 0);
        acc[3][0] = __builtin_amdgcn_mfma_f32_16x16x32_bf16(a3, b0, acc[3][0], 0, 0, 0);
        acc[3][1] = __builtin_amdgcn_mfma_f32_16x16x32_bf16(a3, b1, acc[3][1], 0, 0, 0);
        acc[3][2] = __builtin_amdgcn_mfma_f32_16x16x32_bf16(a3, b2, acc[3][2], 0, 0, 0);
        acc[3][3] = __builtin_amdgcn_mfma_f32_16x16x32_bf16(a3, b3, acc[3][3], 0, 0, 0);
    }
    __hip_bfloat16* V = (__hip_bfloat16*)(ws + OFF_V) + (size_t)g * H_ * H_;
#pragma unroll
    for (int ti = 0; ti < 4; ++ti)
#pragma unroll
        for (int tj = 0; tj < 4; ++tj)
#pragma unroll
            for (int rr = 0; rr < 4; ++rr)
                V[(size_t)(mg * 64 + ti * 16 + q * 4 + rr) * H_ + ng * 64 + tj * 16 + m]
                    = __float2bfloat16(acc[ti][tj][rr]);
}

// ---------------------------------------------------------------------------
// Kernel 4: prep -- levels, counting-sort worklist, zero per-WG flags.
// ---------------------------------------------------------------------------
__global__ void __launch_bounds__(256)
prep(const int* __restrict__ conn, char* __restrict__ ws)
{
    __shared__ int            conn_s[B_ * N_];
    __shared__ unsigned short lvl[B_ * N_];
    __shared__ int            hist[N_];
    __shared__ int            offs[N_ + 1];
    __shared__ int            cursor[N_];
    __shared__ int            mlv;

    int t = threadIdx.x;
    for (int idx = t; idx < B_ * N_; idx += 256) conn_s[idx] = conn[idx];
    for (int l = t; l < N_; l += 256) hist[l] = 0;
    ((unsigned*)(ws + OFF_FLAGS))[t] = 0u;      // zero the 256 round flags
    __syncthreads();
    if (t < B_) {
        int b = t;
        lvl[b * N_] = 0;
        for (int i = 1; i < N_; ++i)
            lvl[b * N_ + i] = lvl[b * N_ + conn_s[b * N_ + i]] + 1;
    }
    __syncthreads();
    for (int idx = t; idx < B_ * N_; idx += 256) {
        if (idx & (N_ - 1)) atomicAdd(&hist[lvl[idx]], 1);
    }
    __syncthreads();
    if (t == 0) {
        int s = 0, ml = 0;
        for (int l = 0; l < N_; ++l) {
            offs[l] = s; s += hist[l];
            if (hist[l] > 0) ml = l;
        }
        offs[N_] = s;
        mlv = ml;
    }
    __syncthreads();
    for (int l = t; l < N_; l += 256) cursor[l] = offs[l];
    __syncthreads();
    int* gpairs = (int*)(ws + OFF_PAIRS);
    for (int idx = t; idx < B_ * N_; idx += 256) {
        int i = idx & (N_ - 1);
        if (i) {
            int b = idx >> 9;
            int L = lvl[idx];
            int pos = atomicAdd(&cursor[L], 1);
            gpairs[pos] = (b << 18) | (i << 9) | conn_s[idx];
        }
    }
    int* goffs = (int*)(ws + OFF_LOFF);
    for (int l = t; l <= N_; l += 256) goffs[l] = offs[l];
    if (t == 0) goffs[N_ + 1] = mlv;
}

// ---------------------------------------------------------------------------
// Kernel 5: level-scheduled scan. 256 WGs = 64 col-slices x 4 pair-groups.
// Barrier = distributed flags: arrival is one sc1 store to a PRIVATE word
// (no same-address RMW contention); detection is thread t polling flags[t]
// (coalesced 64-lane sc1 loads). Relaxed ordering; the compiler's vmcnt(0)
// drain at the pre-arrival __syncthreads orders h/c stores before the flag
// (the protocol that passed r2/r5/r6).
// ---------------------------------------------------------------------------
__global__ void __launch_bounds__(256, 1)
scan_kernel(float* __restrict__ out, char* __restrict__ ws)
{
    extern __shared__ char lds[];
    __bf16* aSwz   = (__bf16*)(lds + L_A);    // 32 KB swizzled A tile
    __bf16* swizzV = (__bf16*)(lds + L_VS);   // 96 KB swizzled V slice
    float*  ldsC   = (float*)(lds + L_C2);

    const int t    = threadIdx.x;
    const int wave = t >> 6;
    const int lane = t & 63;
    const int q = lane >> 4;
    const int m = lane & 15;
    const int cs = blockIdx.x & 63;         // column slice (16 H-cols)
    const int pg = blockIdx.x >> 6;         // pair group (0..3)

    const int* __restrict__ pairsG = (const int*)(ws + OFF_PAIRS);
    const int* __restrict__ offsG  = (const int*)(ws + OFF_LOFF);
    ull*       hbw = (ull*)(ws + OFF_HBF);
    const float* __restrict__ f0 = (const float*)(ws + OFF_F0);
    const float* __restrict__ o0 = f0 + B_ * H_;
    const float* __restrict__ z0 = o0 + B_ * H_;
    ull*      tcu = (ull*)(ws + OFF_C);
    float*    out_f = out;
    unsigned* flagsG = (unsigned*)(ws + OFF_FLAGS);

    // stage V swizzled: chunk j=(g,c,lane) -> V_g[row=cs*16+mm][k=c*32+qq*8..+7]
    const __bf16* Vg = (const __bf16*)(ws + OFF_V);
    for (int j = t; j < 6144; j += 256) {
        int g  = j >> 11;
        int c  = (j >> 6) & 31;
        int ln = j & 63;
        int qq = ln >> 4, mm = ln & 15;
        bf16x8 v = *(const bf16x8*)(Vg + (size_t)g * H_ * H_
                                       + (size_t)(cs * 16 + mm) * H_ + c * 32 + qq * 8);
        *(bf16x8*)(swizzV + (size_t)j * 8) = v;
    }
    __syncthreads();

    const int maxlvl = offsG[N_ + 1];
    const int rid = t & 15;                 // staged pair slot
    const int ck  = t >> 4;                 // 128B chunk within row
    char* stDst = (char*)aSwz + ck * 2048 + rid * 16;
    const char* aB = (const char*)aSwz + lane * 16;
    const __bf16* vbL = swizzV + ((size_t)(wave < 3 ? wave : 0) * 2048 + lane) * 8;
    const intx4* hbv = (const intx4*)(ws + OFF_HBF);

    for (int r = 1; r <= maxlvl; ++r) {
        const int lo = offsG[r], hi = offsG[r + 1];
        const int ntile = (hi - lo + 15) >> 4;
        for (int tt = pg; tt < ntile; tt += 4) {
            const int curTs = lo + (tt << 4);

            // A staging: 8x plain dwordx4 loads per thread (one 128B chunk),
            // pipelined into a single vmcnt window.
            int idx = curTs + rid; if (idx > hi - 1) idx = hi - 1;
            int pk = pairsG[idx];
            const intx4* src = hbv + ((((size_t)((pk >> 18) * N_ + (pk & 511))) * H_) >> 3)
                                   + (size_t)ck * 8;
            intx4 u0 = src[0], u1 = src[1], u2 = src[2], u3 = src[3];
            intx4 u4 = src[4], u5 = src[5], u6 = src[6], u7 = src[7];

            // wave3: parent-c prefetch for this tile (plain 16B load)
            floatx4 pcv = {0.f, 0.f, 0.f, 0.f};
            if (wave == 3) {
                int idx2 = curTs + (lane >> 2); if (idx2 > hi - 1) idx2 = hi - 1;
                int pk2 = pairsG[idx2];
                const float* pca = (const float*)(ws + OFF_C)
                    + ((size_t)((pk2 >> 18) * N_ + (pk2 & 511))) * H_
                    + cs * 16 + (lane & 3) * 4;
                pcv = *(const floatx4*)pca;
            }

            __syncthreads();                // S_a: prev tile fully consumed
            {
                intx4* d = (intx4*)stDst;
                d[0]  = u0; d[16] = u1; d[32] = u2; d[48] = u3;   // stride 256B
                d[64] = u4; d[80] = u5; d[96] = u6; d[112] = u7;
            }
            __syncthreads();                // S_b: aSwz visible

            if (wave < 3) {
                floatx4 acc0 = {0.f,0.f,0.f,0.f}, acc1 = {0.f,0.f,0.f,0.f};
                floatx4 acc2 = {0.f,0.f,0.f,0.f}, acc3 = {0.f,0.f,0.f,0.f};
#pragma unroll
                for (int c = 0; c < 32; ++c) {
                    bf16x8 av = *(const bf16x8*)(aB + c * 1024);
                    bf16x8 bv = *(const bf16x8*)(vbL + c * 512);
                    switch (c & 3) {
                    case 0:  acc0 = __builtin_amdgcn_mfma_f32_16x16x32_bf16(av, bv, acc0, 0, 0, 0); break;
                    case 1:  acc1 = __builtin_amdgcn_mfma_f32_16x16x32_bf16(av, bv, acc1, 0, 0, 0); break;
                    case 2:  acc2 = __builtin_amdgcn_mfma_f32_16x16x32_bf16(av, bv, acc2, 0, 0, 0); break;
                    default: acc3 = __builtin_amdgcn_mfma_f32_16x16x32_bf16(av, bv, acc3, 0, 0, 0); break;
                    }
                }
                floatx4 acc = (acc0 + acc1) + (acc2 + acc3);
                ldsC[(wave * 16 + q * 4 + 0) * 17 + m] = acc[0];
                ldsC[(wave * 16 + q * 4 + 1) * 17 + m] = acc[1];
                ldsC[(wave * 16 + q * 4 + 2) * 17 + m] = acc[2];
                ldsC[(wave * 16 + q * 4 + 3) * 17 + m] = acc[3];
            }
            __syncthreads();                // S_c: ldsC ready

            if (wave == 3) {
                int pr = lane >> 2, n0 = (lane & 3) << 2;
                int idx2 = curTs + pr; if (idx2 > hi - 1) idx2 = hi - 1;
                int pk2 = pairsG[idx2];
                int bb = pk2 >> 18, ii = (pk2 >> 9) & 511;
                int hcol0 = cs * 16 + n0;
                floatx4 fv = *(const floatx4*)&f0[bb * H_ + hcol0];
                floatx4 ov = *(const floatx4*)&o0[bb * H_ + hcol0];
                floatx4 zv = *(const floatx4*)&z0[bb * H_ + hcol0];
                floatx4 cc, hv;
                ull hpack = 0;
#pragma unroll
                for (int j = 0; j < 4; ++j) {
                    float af = ldsC[(0 * 16 + pr) * 17 + n0 + j] + fv[j];
                    float ao = ldsC[(1 * 16 + pr) * 17 + n0 + j] + ov[j];
                    float az = ldsC[(2 * 16 + pr) * 17 + n0 + j] + zv[j];
                    float f = 1.0f / (1.0f + __expf(-af));
                    float o = 1.0f / (1.0f + __expf(-ao));
                    float z = tanhf(az);
                    float c = pcv[j] * f + z * (1.0f - f);
                    float h = o * tanhf(c);
                    cc[j] = c; hv[j] = h;
                    hpack |= (ull)__builtin_bit_cast(unsigned short, __float2bfloat16(h)) << (16 * j);
                }
                size_t idxI = ((size_t)(bb * N_ + ii)) * H_ + hcol0;
                union U2 { ull u; float f[2]; };
                U2 c01, c23;
                c01.f[0] = cc[0]; c01.f[1] = cc[1];
                c23.f[0] = cc[2]; c23.f[1] = cc[3];
                AT_ST(tcu + (idxI >> 1),     c01.u);
                AT_ST(tcu + (idxI >> 1) + 1, c23.u);
                *(floatx4*)&out_f[idxI] = hv;
                AT_ST(hbw + (idxI >> 2), hpack);
            }
        }
        if (r < maxlvl) {
            __syncthreads();                // drains vmcnt -> h/c stores done
            if (t == 0) AT_ST(flagsG + blockIdx.x, (unsigned)r);   // arrival: private word
            {
                unsigned rr = (unsigned)r;
                while (AT_LD(flagsG + t) < rr) { }                 // detection: flags[t]
            }
            __syncthreads();
        }
    }
}

// ---------------------------------------------------------------------------
extern "C" void kernel_launch(void* const* d_in, const int* in_sizes, int n_in,
                              void* d_out, int out_size, void* d_ws, size_t ws_size,
                              hipStream_t stream)
{
    const float* te  = (const float*)d_in[0];
    const int*  conn = (const int*)d_in[1];
    const float* Wf = (const float*)d_in[3];
    const float* bf = (const float*)d_in[4];
    const float* Wo = (const float*)d_in[5];
    const float* bo = (const float*)d_in[6];
    const float* Wz = (const float*)d_in[7];
    const float* bz = (const float*)d_in[8];
    const float* Tf = (const float*)d_in[9];
    const float* To = (const float*)d_in[10];
    const float* Tz = (const float*)d_in[11];
    float* out = (float*)d_out;
    char*  ws  = (char*)d_ws;

    hipFuncSetAttribute((const void*)scan_kernel,
                        hipFuncAttributeMaxDynamicSharedMemorySize, (int)L_TOT);

    t_transpose<<<dim3(768), dim3(256), 0, stream>>>(Tf, To, Tz, ws);
    k0_root<<<dim3(64), dim3(256), 0, stream>>>(te, Wf, bf, Wo, bo, Wz, bz, out, ws);
    v_gemm<<<dim3(768), dim3(64), 0, stream>>>(ws);
    prep<<<dim3(1), dim3(256), 0, stream>>>(conn, ws);

    void* args[] = { (void*)&out, (void*)&ws };
    hipLaunchCooperativeKernel((const void*)scan_kernel, dim3(256), dim3(256),
                               (void**)args, (unsigned)L_TOT, stream);
}